// Round 10
// baseline (243.309 us; speedup 1.0000x reference)
//
#include <hip/hip_runtime.h>
#include <math.h>

#define BB 128
#define SS 256
#define AA 128
#define HH 8
#define CC 16
#define HCC 128
#define OO 128

typedef float f32x4 __attribute__((ext_vector_type(4)));
typedef short s16x4 __attribute__((ext_vector_type(4)));
typedef unsigned short u16x4 __attribute__((ext_vector_type(4)));

__device__ __forceinline__ unsigned bf16_rne(float x) {
    union { float f; unsigned u; } v; v.f = x;
    return (v.u + 0x7fffu + ((v.u >> 16) & 1u)) >> 16;
}
__device__ __forceinline__ unsigned pack_bf16(float lo, float hi) {
    return bf16_rne(lo) | (bf16_rne(hi) << 16);
}

// D = A*B + C, 16x16x16 bf16 (HW-validated rounds 7+9):
// A: row=lane&15, k=(lane>>4)*4+i. B: k=(lane>>4)*4+i, col=lane&15.
// C/D: col=lane&15, row=(lane>>4)*4+reg.
__device__ __forceinline__ void mfma16(f32x4& d, s16x4 a, s16x4 b) {
#if __has_builtin(__builtin_amdgcn_mfma_f32_16x16x16bf16_1k)
    d = __builtin_amdgcn_mfma_f32_16x16x16bf16_1k(a, b, d, 0, 0, 0);
#else
    asm("v_mfma_f32_16x16x16_bf16 %0, %1, %2, %0" : "+v"(d) : "v"(a), "v"(b));
#endif
}

// ---------------- K0: weight prep ----------------
// wt16[j][outch][a] bf16 (transposed W). j<4 (q,k,v,g): LINEAR (read direct
// from global by qkvg). j==4 (wo): XOR-swizzled (byte ^= (outch&7)<<5) for
// conflict-reduced LDS frag reads in the fused attn tail (validated r9).
__global__ __launch_bounds__(256) void prep_w_kernel(
    const float* __restrict__ wq, const float* __restrict__ wk,
    const float* __restrict__ wv, const float* __restrict__ wg,
    const float* __restrict__ wo, unsigned short* __restrict__ wt16)
{
    const int j = blockIdx.x >> 4;                        // matrix 0..4
    const int t = ((blockIdx.x & 15) << 8) + threadIdx.x; // 0..4095
    const float* W = (j == 0) ? wq : (j == 1) ? wk : (j == 2) ? wv
                   : (j == 3) ? wg : wo;
    const int outch = t >> 5;        // 0..127
    const int a0 = (t & 31) * 4;     // 0..124
    u16x4 v;
    #pragma unroll
    for (int u = 0; u < 4; ++u)
        v[u] = (unsigned short)bf16_rne(W[(size_t)(a0 + u) * 128 + outch]);
    int off = a0 * 2;
    if (j == 4) off ^= (outch & 7) << 5;
    *(u16x4*)((char*)wt16 + (size_t)j * 32768 + outch * 256 + off) = v;
}

// ---------------- K1: fused QKVG projection, MFMA, no LDS ----------------
// Weights read DIRECTLY from linear wt16 (32KB/chunk = L1-sized, L2-hot).
// Zero barriers. blockIdx.y splits the 4 chunks 2x2 for 2x the wave count
// (costs one extra qdata read; kernel is latency- not BW-bound).
__global__ __launch_bounds__(256, 4) void qkvg_mfma_kernel(
    const float* __restrict__ qdata, const unsigned short* __restrict__ wt16,
    unsigned short* __restrict__ qb, unsigned short* __restrict__ kb,
    unsigned short* __restrict__ vtb, float* __restrict__ g_ws)
{
    const int tid = threadIdx.x;
    const int w = tid >> 6;
    const int lane = tid & 63;
    const int lo = lane & 15, gg = lane >> 4;
    const int sb = blockIdx.x * 64;
    const int s = sb + w * 16 + lo;
    const int b = sb >> 8;
    const int srow = (sb & 255) + w * 16;

    // 8 k-tile frags of this lane's qdata row (fp32 -> bf16)
    s16x4 qd[8];
    {
        const float* qp = qdata + (size_t)s * AA;
        #pragma unroll
        for (int t = 0; t < 8; ++t) {
            float4 f = *(const float4*)(qp + t * 16 + gg * 4);
            unsigned w0 = pack_bf16(f.x, f.y), w1 = pack_bf16(f.z, f.w);
            s16x4 q; ((unsigned*)&q)[0] = w0; ((unsigned*)&q)[1] = w1;
            qd[t] = q;
        }
    }

    const int m0 = blockIdx.y * 2;
    for (int m = m0; m < m0 + 2; ++m) {
        const unsigned short* wb = wt16 + (size_t)m * 16384;
        #pragma unroll
        for (int cf = 0; cf < 8; ++cf) {
            s16x4 wf[8];
            #pragma unroll
            for (int t = 0; t < 8; ++t)   // element [outch=cf*16+lo][a=t*16+gg*4]
                wf[t] = *(const s16x4*)(wb + (cf * 16 + lo) * 128 + t * 16 + gg * 4);
            f32x4 acc = {0.f, 0.f, 0.f, 0.f};
            if (m == 2) {  // v: unswapped D[s][outch]
                #pragma unroll
                for (int t = 0; t < 8; ++t) mfma16(acc, qd[t], wf[t]);
                u16x4 o;
                #pragma unroll
                for (int r = 0; r < 4; ++r) o[r] = (unsigned short)bf16_rne(acc[r]);
                *(u16x4*)(vtb + (((size_t)b * HH + cf) * CC + lo) * SS
                          + srow + gg * 4) = o;
            } else {       // q/k/g: swapped D[outch][s]
                #pragma unroll
                for (int t = 0; t < 8; ++t) mfma16(acc, wf[t], qd[t]);
                if (m == 0) {
                    u16x4 o;
                    #pragma unroll
                    for (int r = 0; r < 4; ++r)
                        o[r] = (unsigned short)bf16_rne(acc[r] * 0.25f);
                    *(u16x4*)(qb + (((size_t)b * HH + cf) * SS + srow + lo) * CC
                              + gg * 4) = o;
                } else if (m == 1) {
                    u16x4 o;
                    #pragma unroll
                    for (int r = 0; r < 4; ++r) o[r] = (unsigned short)bf16_rne(acc[r]);
                    *(u16x4*)(kb + (((size_t)b * HH + cf) * SS + srow + lo) * CC
                              + gg * 4) = o;
                } else {
                    float4 g;
                    g.x = 1.f / (1.f + __expf(-acc[0]));
                    g.y = 1.f / (1.f + __expf(-acc[1]));
                    g.z = 1.f / (1.f + __expf(-acc[2]));
                    g.w = 1.f / (1.f + __expf(-acc[3]));
                    *(float4*)(g_ws + ((size_t)b * SS + srow + lo) * HCC
                               + cf * 16 + gg * 4) = g;
                }
            }
        }
    }
}

// ---------------- K2: MFMA attention + FUSED output projection ----------------
// Main loop identical to round-9 (validated). Epilogue kept in registers;
// after a block barrier the 64x128 gated tile goes to swizzled LDS, wo is
// staged, and the block does the output GEMM in-place (r9-validated read
// patterns). Eliminates gwa16 roundtrip + the outproj kernel.
__global__ __launch_bounds__(512, 4) void attn_fused_kernel(
    const unsigned short* __restrict__ qb,   // [B][H][S][16] bf16, scaled
    const unsigned short* __restrict__ kb,   // [B][H][S][16] bf16
    const unsigned short* __restrict__ vtb,  // [B][H][16][S] bf16
    const float* __restrict__ g_ws,          // [B][S][128] f32
    const float* __restrict__ bias,          // [B][S][S] f32
    const float* __restrict__ nb,            // [S][S] f32
    const unsigned short* __restrict__ wo16, // [128][128] bf16, XOR<<5 swizzled
    float* __restrict__ out)                 // [B*S][128] f32
{
    __shared__ char smem[65536];
    // phase A: smem = bias+nb quarter [64][256] f32, XOR<<4 row-swizzled
    // phase B: smem[0:16K) = gw tile [64][128] bf16 (XOR<<4), [16K:48K) = wo
    const int tid = threadIdx.x;
    const int blk = blockIdx.x;
    const int b = blk >> 2;
    const int Q0 = (blk & 3) * 64;

    {   // stage bias+nb, coalesced; byte ^= (row&7)<<4
        const float4* bsrc = (const float4*)(bias + ((size_t)b * SS + Q0) * SS);
        const float4* nsrc = (const float4*)(nb + (size_t)Q0 * SS);
        #pragma unroll
        for (int i = 0; i < 8; ++i) {
            int idx = i * 512 + tid;
            int r = idx >> 6, c4 = idx & 63;
            float4 bv = bsrc[idx];
            float4 nv = nsrc[idx];
            bv.x += nv.x; bv.y += nv.y; bv.z += nv.z; bv.w += nv.w;
            int byteoff = r * 1024 + ((c4 * 16) ^ ((r & 7) << 4));
            *(float4*)(smem + byteoff) = bv;
        }
    }
    __syncthreads();

    const int wv = tid >> 6;          // head
    const int lane = tid & 63;
    const int lo = lane & 15, gg = lane >> 4;
    const size_t bh = (size_t)b * HH + wv;

    s16x4 kf[16], vf[16];
    {
        const unsigned short* kp = kb + bh * SS * CC;
        const unsigned short* vp = vtb + bh * CC * SS;
        #pragma unroll
        for (int t = 0; t < 16; ++t)
            kf[t] = *(const s16x4*)(kp + (t * 16 + lo) * CC + gg * 4);
        #pragma unroll
        for (int t = 0; t < 16; ++t)
            vf[t] = *(const s16x4*)(vp + lo * SS + t * 16 + gg * 4);
    }
    const unsigned short* qp = qb + bh * SS * CC;

    f32x4 ov[4];   // gated output per qt, held until post-barrier LDS dump
    for (int qt = 0; qt < 4; ++qt) {
        const int qrow = Q0 + qt * 16 + lo;
        s16x4 qf = *(const s16x4*)(qp + qrow * CC + gg * 4);
        const int rl = qt * 16 + lo;
        f32x4 S[16];
        #pragma unroll
        for (int t = 0; t < 16; ++t) {
            int byteoff = rl * 1024 + (((t * 4 + gg) * 16) ^ ((rl & 7) << 4));
            S[t] = *(const f32x4*)(smem + byteoff);
        }
        #pragma unroll
        for (int t = 0; t < 16; ++t) mfma16(S[t], kf[t], qf);
        asm volatile("s_nop 7\n\ts_nop 7");

        float lsum = 0.f;
        unsigned pw[32];
        #pragma unroll
        for (int t = 0; t < 16; ++t) {
            float p0 = __expf(S[t][0] - 12.f), p1 = __expf(S[t][1] - 12.f);
            float p2 = __expf(S[t][2] - 12.f), p3 = __expf(S[t][3] - 12.f);
            lsum += (p0 + p1) + (p2 + p3);
            pw[t * 2]     = pack_bf16(p0, p1);
            pw[t * 2 + 1] = pack_bf16(p2, p3);
        }
        lsum += __shfl_xor(lsum, 16);
        lsum += __shfl_xor(lsum, 32);

        f32x4 W0 = {0.f, 0.f, 0.f, 0.f}, W1 = {0.f, 0.f, 0.f, 0.f};
        asm volatile("s_nop 7");
        #pragma unroll
        for (int t = 0; t < 16; t += 2) {
            s16x4 pa; ((unsigned*)&pa)[0] = pw[t * 2];     ((unsigned*)&pa)[1] = pw[t * 2 + 1];
            mfma16(W0, vf[t], pa);
            s16x4 pb; ((unsigned*)&pb)[0] = pw[t * 2 + 2]; ((unsigned*)&pb)[1] = pw[t * 2 + 3];
            mfma16(W1, vf[t + 1], pb);
        }
        asm volatile("s_nop 7\n\ts_nop 7");

        const float inv = 1.f / lsum;
        float4 gt = *(const float4*)(g_ws + ((size_t)b * SS + qrow) * HCC
                                     + wv * 16 + gg * 4);
        f32x4 o;
        o[0] = (W0[0] + W1[0]) * inv * gt.x;
        o[1] = (W0[1] + W1[1]) * inv * gt.y;
        o[2] = (W0[2] + W1[2]) * inv * gt.z;
        o[3] = (W0[3] + W1[3]) * inv * gt.w;
        ov[qt] = o;
    }

    __syncthreads();   // all bias reads done; smem is now free
    {   // dump gated tile -> gw_lds [64 rows][128 c] bf16, byte ^= (row&7)<<4
        #pragma unroll
        for (int qt = 0; qt < 4; ++qt) {
            int rl = qt * 16 + lo;
            uint2 pk;
            pk.x = pack_bf16(ov[qt][0], ov[qt][1]);
            pk.y = pack_bf16(ov[qt][2], ov[qt][3]);
            int byteoff = rl * 256 + ((wv * 32 + gg * 8) ^ ((rl & 7) << 4));
            *(uint2*)(smem + byteoff) = pk;
        }
        // stage wo (pre-swizzled) into smem[16K..48K), linear 32KB copy
        const uint4* src = (const uint4*)wo16;
        uint4* dst = (uint4*)(smem + 16384);
        #pragma unroll
        for (int i = 0; i < 4; ++i) dst[i * 512 + tid] = src[i * 512 + tid];
    }
    __syncthreads();

    // output projection tile: wave w -> row-tile rt = w&3, out-tiles (w>>2)*4..+3
    {
        const int rt = wv & 3;
        const int ob = (wv >> 2) * 4;
        const int r = rt * 16 + lo;
        const int orow = ((size_t)0, Q0) + rt * 16 + lo;  // row within quarter
        #pragma unroll
        for (int oi = 0; oi < 4; ++oi) {
            const int ot = ob + oi;
            f32x4 acc = {0.f, 0.f, 0.f, 0.f};
            #pragma unroll
            for (int kt = 0; kt < 8; ++kt) {
                // A = wo[out=ot*16+lo][a=kt*16+gg*4], swizzle <<5 (r9-validated)
                s16x4 wf = *(const s16x4*)(smem + 16384 + (ot * 16 + lo) * 256
                             + ((kt * 32 + gg * 8) ^ ((lo & 7) << 5)));
                // B = gw[row=rt*16+lo][c=kt*16+gg*4], swizzle <<4 (both-sides)
                s16x4 gb = *(const s16x4*)(smem + r * 256
                             + ((kt * 32 + gg * 8) ^ ((r & 7) << 4)));
                mfma16(acc, wf, gb);
            }
            // swapped D[out][s]: lane -> s = rt*16+lo, out = ot*16+gg*4+reg
            float4 o4; o4.x = acc[0]; o4.y = acc[1]; o4.z = acc[2]; o4.w = acc[3];
            *(float4*)(out + ((size_t)b * SS + Q0 + rt * 16 + lo) * OO
                       + ot * 16 + gg * 4) = o4;
        }
    }
}

extern "C" void kernel_launch(void* const* d_in, const int* in_sizes, int n_in,
                              void* d_out, int out_size, void* d_ws, size_t ws_size,
                              hipStream_t stream) {
    const float* qdata = (const float*)d_in[0];
    const float* bias  = (const float*)d_in[1];
    const float* nb    = (const float*)d_in[2];
    const float* wq    = (const float*)d_in[3];
    const float* wk    = (const float*)d_in[4];
    const float* wv    = (const float*)d_in[5];
    const float* wg    = (const float*)d_in[6];
    const float* wo    = (const float*)d_in[7];
    float* out = (float*)d_out;

    const size_t QKV = (size_t)BB * HH * SS * CC;   // 4,194,304 elements
    unsigned short* qb   = (unsigned short*)d_ws;
    unsigned short* kbp  = qb + QKV;
    unsigned short* vtb  = kbp + QKV;
    unsigned short* wt16 = vtb + QKV;               // 5*16384 ushorts
    float* g_ws = (float*)(wt16 + 5 * 16384);       // 16B-aligned
    // total ~42 MB workspace

    prep_w_kernel<<<dim3(80), dim3(256), 0, stream>>>(wq, wk, wv, wg, wo, wt16);
    qkvg_mfma_kernel<<<dim3((BB * SS) / 64, 2), dim3(256), 0, stream>>>(
        qdata, wt16, qb, kbp, vtb, g_ws);
    attn_fused_kernel<<<dim3(BB * 4), dim3(512), 0, stream>>>(
        qb, kbp, vtb, g_ws, bias, nb, wt16 + 4 * 16384, out);
}

// Round 11
// 148.809 us; speedup vs baseline: 1.6350x; 1.6350x over previous
//
#include <hip/hip_runtime.h>
#include <math.h>

#define BB 128
#define SS 256
#define AA 128
#define HH 8
#define CC 16
#define HCC 128
#define OO 128

typedef float f32x4 __attribute__((ext_vector_type(4)));
typedef short s16x4 __attribute__((ext_vector_type(4)));
typedef unsigned short u16x4 __attribute__((ext_vector_type(4)));

__device__ __forceinline__ unsigned bf16_rne(float x) {
    union { float f; unsigned u; } v; v.f = x;
    return (v.u + 0x7fffu + ((v.u >> 16) & 1u)) >> 16;
}
__device__ __forceinline__ unsigned pack_bf16(float lo, float hi) {
    return bf16_rne(lo) | (bf16_rne(hi) << 16);
}

// D = A*B + C, 16x16x16 bf16 (HW-validated rounds 7/9/10):
// A: row=lane&15, k=(lane>>4)*4+i. B: k=(lane>>4)*4+i, col=lane&15.
// C/D: col=lane&15, row=(lane>>4)*4+reg.
__device__ __forceinline__ void mfma16(f32x4& d, s16x4 a, s16x4 b) {
#if __has_builtin(__builtin_amdgcn_mfma_f32_16x16x16bf16_1k)
    d = __builtin_amdgcn_mfma_f32_16x16x16bf16_1k(a, b, d, 0, 0, 0);
#else
    asm("v_mfma_f32_16x16x16_bf16 %0, %1, %2, %0" : "+v"(d) : "v"(a), "v"(b));
#endif
}

// ---------------- K0: weight prep ----------------
// wt16[j][outch][a] bf16 (transposed), ALL matrices XOR-swizzled:
// byte = j*32768 + outch*256 + ((a*2) ^ ((outch&7)<<5))   [r9-validated]
// -> LDS staging is a LINEAR copy; frag reads use the same XOR.
__global__ __launch_bounds__(256) void prep_w_kernel(
    const float* __restrict__ wq, const float* __restrict__ wk,
    const float* __restrict__ wv, const float* __restrict__ wg,
    const float* __restrict__ wo, unsigned short* __restrict__ wt16)
{
    const int j = blockIdx.x >> 4;                        // matrix 0..4
    const int t = ((blockIdx.x & 15) << 8) + threadIdx.x; // 0..4095
    const float* W = (j == 0) ? wq : (j == 1) ? wk : (j == 2) ? wv
                   : (j == 3) ? wg : wo;
    const int outch = t >> 5;        // 0..127
    const int a0 = (t & 31) * 4;     // 0..124
    u16x4 v;
    #pragma unroll
    for (int u = 0; u < 4; ++u)
        v[u] = (unsigned short)bf16_rne(W[(size_t)(a0 + u) * 128 + outch]);
    *(u16x4*)((char*)wt16 + (size_t)j * 32768 + outch * 256
              + ((a0 * 2) ^ ((outch & 7) << 5))) = v;
}

// ---------------- K1: fused QKVG projection, MFMA ----------------
// 128 s-rows/block, 8 waves; ONE 64KB stage (chunk-pair via blockIdx.y) and
// ONE barrier, then all 8 waves run barrier-free. Grid 256x2 = 512 blocks
// = exactly 2 resident/CU (64KB LDS). Frag/store patterns byte-identical
// to the r9-validated kernel. NO direct-global weight reads (r10 lesson:
// lane-strided 256B reads are latency-death), no launch_bounds VGPR squeeze
// (r10 lesson: spills cost 3x more than occupancy buys).
__global__ __launch_bounds__(512, 2) void qkvg_mfma_kernel(
    const float* __restrict__ qdata, const unsigned short* __restrict__ wt16,
    unsigned short* __restrict__ qb, unsigned short* __restrict__ kb,
    unsigned short* __restrict__ vtb, float* __restrict__ g_ws)
{
    __shared__ char wlds[65536];
    const int tid = threadIdx.x;
    const int w = tid >> 6;
    const int lane = tid & 63;
    const int lo = lane & 15, gg = lane >> 4;
    const int sb = blockIdx.x * 128;
    const int s = sb + w * 16 + lo;
    const int b = sb >> 8;                 // 128 | 256 -> block-uniform
    const int srow = (sb & 255) + w * 16;
    const int m0 = blockIdx.y * 2;         // {q,k} or {v,g}

    {   // stage BOTH chunks of this pair: linear 64KB copy (source pre-swizzled)
        const uint4* src = (const uint4*)(wt16 + (size_t)m0 * 16384);
        uint4* dst = (uint4*)wlds;
        #pragma unroll
        for (int i = 0; i < 8; ++i) dst[i * 512 + tid] = src[i * 512 + tid];
    }

    // 8 k-tile frags of this lane's qdata row (fp32 -> bf16) — overlaps stage
    s16x4 qd[8];
    {
        const float* qp = qdata + (size_t)s * AA;
        #pragma unroll
        for (int t = 0; t < 8; ++t) {
            float4 f = *(const float4*)(qp + t * 16 + gg * 4);
            unsigned w0 = pack_bf16(f.x, f.y), w1 = pack_bf16(f.z, f.w);
            s16x4 q; ((unsigned*)&q)[0] = w0; ((unsigned*)&q)[1] = w1;
            qd[t] = q;
        }
    }
    __syncthreads();   // the only barrier

    for (int mi = 0; mi < 2; ++mi) {
        const int m = m0 + mi;
        const char* wbase = wlds + mi * 32768;
        #pragma unroll
        for (int cf = 0; cf < 8; ++cf) {
            s16x4 wf[8];
            #pragma unroll
            for (int t = 0; t < 8; ++t) {
                int boff = (cf * 16 + lo) * 256 + ((t * 32 + gg * 8) ^ ((lo & 7) << 5));
                wf[t] = *(const s16x4*)(wbase + boff);
            }
            f32x4 acc = {0.f, 0.f, 0.f, 0.f};
            if (m == 2) {  // v: unswapped D[s][outch] -> transposed store
                #pragma unroll
                for (int t = 0; t < 8; ++t) mfma16(acc, qd[t], wf[t]);
                u16x4 o;
                #pragma unroll
                for (int r = 0; r < 4; ++r) o[r] = (unsigned short)bf16_rne(acc[r]);
                *(u16x4*)(vtb + (((size_t)b * HH + cf) * CC + lo) * SS
                          + srow + gg * 4) = o;
            } else {       // q/k/g: swapped D[outch][s]
                #pragma unroll
                for (int t = 0; t < 8; ++t) mfma16(acc, wf[t], qd[t]);
                if (m == 0) {
                    u16x4 o;
                    #pragma unroll
                    for (int r = 0; r < 4; ++r)
                        o[r] = (unsigned short)bf16_rne(acc[r] * 0.25f);
                    *(u16x4*)(qb + (((size_t)b * HH + cf) * SS + srow + lo) * CC
                              + gg * 4) = o;
                } else if (m == 1) {
                    u16x4 o;
                    #pragma unroll
                    for (int r = 0; r < 4; ++r) o[r] = (unsigned short)bf16_rne(acc[r]);
                    *(u16x4*)(kb + (((size_t)b * HH + cf) * SS + srow + lo) * CC
                              + gg * 4) = o;
                } else {
                    float4 g;
                    g.x = 1.f / (1.f + __expf(-acc[0]));
                    g.y = 1.f / (1.f + __expf(-acc[1]));
                    g.z = 1.f / (1.f + __expf(-acc[2]));
                    g.w = 1.f / (1.f + __expf(-acc[3]));
                    *(float4*)(g_ws + ((size_t)b * SS + srow + lo) * HCC
                               + cf * 16 + gg * 4) = g;
                }
            }
        }
    }
}

// ---------------- K2: MFMA attention + FUSED output projection ----------------
// r10 logic (correctness-validated) at r9's occupancy config (512,2):
// VGPR cap 256 -> no spills (r10 lesson: (512,4) forced VGPR=64 and +149MB
// of scratch HBM traffic).
__global__ __launch_bounds__(512, 2) void attn_fused_kernel(
    const unsigned short* __restrict__ qb,   // [B][H][S][16] bf16, scaled
    const unsigned short* __restrict__ kb,   // [B][H][S][16] bf16
    const unsigned short* __restrict__ vtb,  // [B][H][16][S] bf16
    const float* __restrict__ g_ws,          // [B][S][128] f32
    const float* __restrict__ bias,          // [B][S][S] f32
    const float* __restrict__ nb,            // [S][S] f32
    const unsigned short* __restrict__ wo16, // [128][128] bf16, XOR<<5 swizzled
    float* __restrict__ out)                 // [B*S][128] f32
{
    __shared__ char smem[65536];
    // phase A: smem = bias+nb quarter [64][256] f32, XOR<<4 row-swizzled
    // phase B: smem[0:16K) = gw tile [64][128] bf16 (XOR<<4), [16K:48K) = wo
    const int tid = threadIdx.x;
    const int blk = blockIdx.x;
    const int b = blk >> 2;
    const int Q0 = (blk & 3) * 64;

    {   // stage bias+nb, coalesced; byte ^= (row&7)<<4
        const float4* bsrc = (const float4*)(bias + ((size_t)b * SS + Q0) * SS);
        const float4* nsrc = (const float4*)(nb + (size_t)Q0 * SS);
        #pragma unroll
        for (int i = 0; i < 8; ++i) {
            int idx = i * 512 + tid;
            int r = idx >> 6, c4 = idx & 63;
            float4 bv = bsrc[idx];
            float4 nv = nsrc[idx];
            bv.x += nv.x; bv.y += nv.y; bv.z += nv.z; bv.w += nv.w;
            int byteoff = r * 1024 + ((c4 * 16) ^ ((r & 7) << 4));
            *(float4*)(smem + byteoff) = bv;
        }
    }
    __syncthreads();

    const int wv = tid >> 6;          // head
    const int lane = tid & 63;
    const int lo = lane & 15, gg = lane >> 4;
    const size_t bh = (size_t)b * HH + wv;

    s16x4 kf[16], vf[16];
    {
        const unsigned short* kp = kb + bh * SS * CC;
        const unsigned short* vp = vtb + bh * CC * SS;
        #pragma unroll
        for (int t = 0; t < 16; ++t)
            kf[t] = *(const s16x4*)(kp + (t * 16 + lo) * CC + gg * 4);
        #pragma unroll
        for (int t = 0; t < 16; ++t)
            vf[t] = *(const s16x4*)(vp + lo * SS + t * 16 + gg * 4);
    }
    const unsigned short* qp = qb + bh * SS * CC;

    f32x4 ov[4];   // gated output per qt, held until post-barrier LDS dump
    for (int qt = 0; qt < 4; ++qt) {
        const int qrow = Q0 + qt * 16 + lo;
        s16x4 qf = *(const s16x4*)(qp + qrow * CC + gg * 4);
        const int rl = qt * 16 + lo;
        f32x4 S[16];
        #pragma unroll
        for (int t = 0; t < 16; ++t) {
            int byteoff = rl * 1024 + (((t * 4 + gg) * 16) ^ ((rl & 7) << 4));
            S[t] = *(const f32x4*)(smem + byteoff);
        }
        #pragma unroll
        for (int t = 0; t < 16; ++t) mfma16(S[t], kf[t], qf);
        asm volatile("s_nop 7\n\ts_nop 7");

        float lsum = 0.f;
        unsigned pw[32];
        #pragma unroll
        for (int t = 0; t < 16; ++t) {
            float p0 = __expf(S[t][0] - 12.f), p1 = __expf(S[t][1] - 12.f);
            float p2 = __expf(S[t][2] - 12.f), p3 = __expf(S[t][3] - 12.f);
            lsum += (p0 + p1) + (p2 + p3);
            pw[t * 2]     = pack_bf16(p0, p1);
            pw[t * 2 + 1] = pack_bf16(p2, p3);
        }
        lsum += __shfl_xor(lsum, 16);
        lsum += __shfl_xor(lsum, 32);

        f32x4 W0 = {0.f, 0.f, 0.f, 0.f}, W1 = {0.f, 0.f, 0.f, 0.f};
        asm volatile("s_nop 7");
        #pragma unroll
        for (int t = 0; t < 16; t += 2) {
            s16x4 pa; ((unsigned*)&pa)[0] = pw[t * 2];     ((unsigned*)&pa)[1] = pw[t * 2 + 1];
            mfma16(W0, vf[t], pa);
            s16x4 pb; ((unsigned*)&pb)[0] = pw[t * 2 + 2]; ((unsigned*)&pb)[1] = pw[t * 2 + 3];
            mfma16(W1, vf[t + 1], pb);
        }
        asm volatile("s_nop 7\n\ts_nop 7");

        const float inv = 1.f / lsum;
        float4 gt = *(const float4*)(g_ws + ((size_t)b * SS + qrow) * HCC
                                     + wv * 16 + gg * 4);
        f32x4 o;
        o[0] = (W0[0] + W1[0]) * inv * gt.x;
        o[1] = (W0[1] + W1[1]) * inv * gt.y;
        o[2] = (W0[2] + W1[2]) * inv * gt.z;
        o[3] = (W0[3] + W1[3]) * inv * gt.w;
        ov[qt] = o;
    }

    __syncthreads();   // all bias reads done; smem is free
    {   // dump gated tile -> [64 rows][128 c] bf16, byte ^= (row&7)<<4
        #pragma unroll
        for (int qt = 0; qt < 4; ++qt) {
            int rl = qt * 16 + lo;
            uint2 pk;
            pk.x = pack_bf16(ov[qt][0], ov[qt][1]);
            pk.y = pack_bf16(ov[qt][2], ov[qt][3]);
            int byteoff = rl * 256 + ((wv * 32 + gg * 8) ^ ((rl & 7) << 4));
            *(uint2*)(smem + byteoff) = pk;
        }
        // stage wo (pre-swizzled) into smem[16K..48K), linear 32KB copy
        const uint4* src = (const uint4*)wo16;
        uint4* dst = (uint4*)(smem + 16384);
        #pragma unroll
        for (int i = 0; i < 4; ++i) dst[i * 512 + tid] = src[i * 512 + tid];
    }
    __syncthreads();

    // output projection: wave -> row-tile rt = wv&3, out-tiles (wv>>2)*4..+3
    {
        const int rt = wv & 3;
        const int ob = (wv >> 2) * 4;
        const int r = rt * 16 + lo;
        #pragma unroll
        for (int oi = 0; oi < 4; ++oi) {
            const int ot = ob + oi;
            f32x4 acc = {0.f, 0.f, 0.f, 0.f};
            #pragma unroll
            for (int kt = 0; kt < 8; ++kt) {
                // A = wo[out=ot*16+lo][a=kt*16+gg*4], swizzle <<5 (validated)
                s16x4 wf = *(const s16x4*)(smem + 16384 + (ot * 16 + lo) * 256
                             + ((kt * 32 + gg * 8) ^ ((lo & 7) << 5)));
                // B = gw[row=rt*16+lo][c=kt*16+gg*4], swizzle <<4 (both-sides)
                s16x4 gb = *(const s16x4*)(smem + r * 256
                             + ((kt * 32 + gg * 8) ^ ((r & 7) << 4)));
                mfma16(acc, wf, gb);
            }
            // swapped D[out][s]: lane -> s = rt*16+lo, out = ot*16+gg*4+reg
            float4 o4; o4.x = acc[0]; o4.y = acc[1]; o4.z = acc[2]; o4.w = acc[3];
            *(float4*)(out + ((size_t)b * SS + Q0 + rt * 16 + lo) * OO
                       + ot * 16 + gg * 4) = o4;
        }
    }
}

extern "C" void kernel_launch(void* const* d_in, const int* in_sizes, int n_in,
                              void* d_out, int out_size, void* d_ws, size_t ws_size,
                              hipStream_t stream) {
    const float* qdata = (const float*)d_in[0];
    const float* bias  = (const float*)d_in[1];
    const float* nb    = (const float*)d_in[2];
    const float* wq    = (const float*)d_in[3];
    const float* wk    = (const float*)d_in[4];
    const float* wv    = (const float*)d_in[5];
    const float* wg    = (const float*)d_in[6];
    const float* wo    = (const float*)d_in[7];
    float* out = (float*)d_out;

    const size_t QKV = (size_t)BB * HH * SS * CC;   // 4,194,304 elements
    unsigned short* qb   = (unsigned short*)d_ws;
    unsigned short* kbp  = qb + QKV;
    unsigned short* vtb  = kbp + QKV;
    unsigned short* wt16 = vtb + QKV;               // 5*16384 ushorts
    float* g_ws = (float*)(wt16 + 5 * 16384);       // 16B-aligned
    // total ~42 MB workspace

    prep_w_kernel<<<dim3(80), dim3(256), 0, stream>>>(wq, wk, wv, wg, wo, wt16);
    qkvg_mfma_kernel<<<dim3((BB * SS) / 128, 2), dim3(512), 0, stream>>>(
        qdata, wt16, qb, kbp, vtb, g_ws);
    attn_fused_kernel<<<dim3(BB * 4), dim3(512), 0, stream>>>(
        qb, kbp, vtb, g_ws, bias, nb, wt16 + 4 * 16384, out);
}